// Round 4
// baseline (587.190 us; speedup 1.0000x reference)
//
#include <hip/hip_runtime.h>
#include <hip/hip_bf16.h>

// Problem constants
#define NQ 32768
#define MI 2048
#define DD 512

typedef unsigned int u32;
typedef unsigned short u16;
typedef unsigned long long u64;

typedef __attribute__((ext_vector_type(8))) short bf16x8;  // 8 bf16 = 4 VGPRs
typedef __attribute__((ext_vector_type(4))) float f32x4;

// ---------------- helpers ----------------

__device__ __forceinline__ u16 f2bf_rne(float f) {
  u32 u = __builtin_bit_cast(u32, f);
  u += 0x7FFFu + ((u >> 16) & 1u);
  return (u16)(u >> 16);
}

__device__ __forceinline__ u16 f2h(float f) {
  return __builtin_bit_cast(u16, (_Float16)f);  // v_cvt_f16_f32 (RNE)
}

__device__ __forceinline__ float h2f(u16 h) {
  return (float)__builtin_bit_cast(_Float16, h);
}

__device__ __forceinline__ void gload16(const void* g, void* l) {
  const __attribute__((address_space(1))) u32* gp =
      (const __attribute__((address_space(1))) u32*)g;
  __attribute__((address_space(3))) u32* lp =
      (__attribute__((address_space(3))) u32*)(u32)(size_t)l;
  __builtin_amdgcn_global_load_lds(gp, lp, 16, 0, 0);
}

// ---------------- kernel 0: fp32 -> bf16 convert ----------------

__global__ __launch_bounds__(256) void cvt_kernel(const float* __restrict__ in,
                                                  u16* __restrict__ out, int n8) {
  int stride = gridDim.x * blockDim.x;
  for (int i = blockIdx.x * blockDim.x + threadIdx.x; i < n8; i += stride) {
    const f32x4* p = (const f32x4*)in + (size_t)i * 2;
    f32x4 a = p[0], b = p[1];
    uint4 o;
    o.x = (u32)f2bf_rne(a[0]) | ((u32)f2bf_rne(a[1]) << 16);
    o.y = (u32)f2bf_rne(a[2]) | ((u32)f2bf_rne(a[3]) << 16);
    o.z = (u32)f2bf_rne(b[0]) | ((u32)f2bf_rne(b[1]) << 16);
    o.w = (u32)f2bf_rne(b[2]) | ((u32)f2bf_rne(b[3]) << 16);
    ((uint4*)out)[i] = o;
  }
}

// ---------------- kernel 1: bf16 GEMM -> packed fp16 row-pairs ----------------
// 2-phase prefetch (T3 minimum recipe): double-buffered LDS, next tile's
// global_load_lds issued BEFORE the current tile's ds_read+MFMA, ONE barrier
// per K-step. 128x128 tile, BK=64, 4 waves (2x2 of 64x64).

__global__ __launch_bounds__(256) void gemm_kernel(const u16* __restrict__ Qb,
                                                   const u16* __restrict__ Mb,
                                                   u32* __restrict__ SP) {
  __shared__ u16 As[2][128 * 64];
  __shared__ u16 Bs[2][128 * 64];
  const int t = threadIdx.x;
  const int l = t & 63, w = t >> 6;
  const int wr = w >> 1, wc = w & 1;
  // chunked XCD swizzle: 4096 blocks, 512 contiguous work-ids per XCD
  const int bid = blockIdx.x;
  const int nb = (bid & 7) * 512 + (bid >> 3);
  const int bm = nb >> 4, bn = nb & 15;

  f32x4 acc[4][4] = {};
  const int l15 = l & 15, lg = l >> 4;

  const u16* Ag = Qb + (size_t)(bm * 128 + (t >> 3)) * DD + (t & 7) * 8;
  const u16* Bg = Mb + (size_t)(bn * 128 + (t >> 3)) * DD + (t & 7) * 8;

#define STAGE(buf, kt)                                                      \
  {                                                                         \
    _Pragma("unroll") for (int i = 0; i < 4; ++i) {                         \
      gload16(Ag + (size_t)i * 32 * DD + (kt), (char*)As[buf] + t * 16 + i * 4096); \
      gload16(Bg + (size_t)i * 32 * DD + (kt), (char*)Bs[buf] + t * 16 + i * 4096); \
    }                                                                       \
  }

  STAGE(0, 0);
  __syncthreads();  // vmcnt(0) drain: buf0 ready

#pragma unroll
  for (int t8 = 0; t8 < 8; ++t8) {
    const int cur = t8 & 1;
    if (t8 < 7) STAGE(cur ^ 1, (t8 + 1) * 64);  // prefetch flies during compute
#pragma unroll
    for (int ks = 0; ks < 2; ++ks) {
      const int kk = ks * 32 + lg * 8;
      bf16x8 af[4], bfr[4];
#pragma unroll
      for (int mi = 0; mi < 4; ++mi)
        af[mi] = *(const bf16x8*)&As[cur][(wr * 64 + mi * 16 + l15) * 64 + kk];
#pragma unroll
      for (int ni = 0; ni < 4; ++ni)
        bfr[ni] = *(const bf16x8*)&Bs[cur][(wc * 64 + ni * 16 + l15) * 64 + kk];
#pragma unroll
      for (int mi = 0; mi < 4; ++mi)
#pragma unroll
        for (int ni = 0; ni < 4; ++ni)
          acc[mi][ni] = __builtin_amdgcn_mfma_f32_16x16x32_bf16(
              af[mi], bfr[ni], acc[mi][ni], 0, 0, 0);
    }
    // single barrier/K-step: __syncthreads' vmcnt(0)+lgkmcnt(0) drain ensures
    // (a) this iter's prefetch landed, (b) all waves done reading buf[cur]
    // before the next iter's STAGE overwrites it.
    if (t8 < 7) __syncthreads();
  }
#undef STAGE

  // epilogue: C/D layout col=lane&15, row=(lane>>4)*4+reg (m89-verified).
  const int r0 = bm * 128 + wr * 64 + (l >> 4) * 4;
  const int c0 = bn * 128 + wc * 64 + l15;
  const int p0 = r0 >> 1;
#pragma unroll
  for (int mi = 0; mi < 4; ++mi)
#pragma unroll
    for (int ni = 0; ni < 4; ++ni) {
      u32 lo = (u32)f2h(acc[mi][ni][0]) | ((u32)f2h(acc[mi][ni][1]) << 16);
      u32 hi = (u32)f2h(acc[mi][ni][2]) | ((u32)f2h(acc[mi][ni][3]) << 16);
      size_t base = (size_t)(p0 + mi * 8) * MI + (c0 + ni * 16);
      SP[base] = lo;
      SP[base + MI] = hi;
    }
}

// ---------------- kernel 2: top-16 select + group-parallel rescore ----------------
// One wave per row n; p=n>>1, h=n&1 pick the fp16 half of SP[p][*].
// Lane l, slot s (0..31): m = (s>>2)*256 + l*4 + (s&3).

#define MAX8T(b) fmaxf(fmaxf(fmaxf(k[b], k[b + 1]), fmaxf(k[b + 2], k[b + 3])), \
                       fmaxf(fmaxf(k[b + 4], k[b + 5]), fmaxf(k[b + 6], k[b + 7])))

#define REMOVE_GRP(b, gvar)                                   \
  {                                                           \
    _Pragma("unroll") for (int j = 0; j < 8; ++j)             \
        k[b + j] = (k[b + j] == gmax) ? -3e38f : k[b + j];    \
    gvar = MAX8T(b);                                          \
  }

__global__ __launch_bounds__(256) void finish_kernel(const float* __restrict__ q,
                                                     const float* __restrict__ m_items,
                                                     const u32* __restrict__ SP,
                                                     float* __restrict__ out) {
  const int w = threadIdx.x >> 6, l = threadIdx.x & 63;
  const int n = blockIdx.x * 4 + w;
  const int p = n >> 1, h = n & 1;

  const uint4* Sr = (const uint4*)(SP + (size_t)p * MI);
  float k[32];
#pragma unroll
  for (int i = 0; i < 8; ++i) {
    uint4 c = Sr[i * 64 + l];
    u32 wd[4] = {c.x, c.y, c.z, c.w};
#pragma unroll
    for (int j = 0; j < 4; ++j) {
      u16 hb = h ? (u16)(wd[j] >> 16) : (u16)(wd[j] & 0xFFFFu);
      float f = h2f(hb);
      int s = i * 4 + j;
      // slot tag in 5 low mantissa bits (scores fp16-derived: distinct scores
      // differ at bit>=13, tag never flips an ordering)
      k[s] = __builtin_bit_cast(float,
                                (__builtin_bit_cast(u32, f) & ~31u) | (u32)(31 - s));
    }
  }

  // row max + sumexp
  float mx = k[0];
#pragma unroll
  for (int j = 1; j < 32; ++j) mx = fmaxf(mx, k[j]);
  for (int off = 32; off >= 1; off >>= 1) mx = fmaxf(mx, __shfl_xor(mx, off));
  float se = 0.f;
#pragma unroll
  for (int j = 0; j < 32; ++j) se += __expf(k[j] - mx);
  for (int off = 32; off >= 1; off >>= 1) se += __shfl_xor(se, off);
  const float invZ = 1.0f / se;

  // group maxima (4 groups of 8)
  float g0 = MAX8T(0), g1 = MAX8T(8), g2 = MAX8T(16), g3 = MAX8T(24);
  float pk = fmaxf(fmaxf(g0, g1), fmaxf(g2, g3));

  int mym = 0x7FFFFFFF;
#pragma unroll 1
  for (int c = 0; c < 16; ++c) {
    float gmax = pk;
    for (int off = 32; off >= 1; off >>= 1) gmax = fmaxf(gmax, __shfl_xor(gmax, off));
    u32 gb = __builtin_bit_cast(u32, gmax);
    int jw = 31 - (int)(gb & 31u);
    u64 bal = __ballot(pk == gmax);
    int wl = (int)__ffsll(bal) - 1;
    int mwin = ((jw >> 2) << 8) + wl * 4 + (jw & 3);
    if (l == c) mym = mwin;
    int grp = __builtin_amdgcn_readfirstlane(jw >> 3);
    switch (grp) {
      case 0: REMOVE_GRP(0, g0); break;
      case 1: REMOVE_GRP(8, g1); break;
      case 2: REMOVE_GRP(16, g2); break;
      default: REMOVE_GRP(24, g3); break;
    }
    pk = fmaxf(fmaxf(g0, g1), fmaxf(g2, g3));
  }

  // group-parallel fp32 rescore: 4-lane group g = l>>2 handles candidate g;
  // each lane dots 128 contiguous floats. Serial shfl depth: 96 -> 3.
  const int mg = __shfl(mym, l >> 2);
  float mysc;
  {
    const f32x4* Mr = (const f32x4*)(m_items + (size_t)mg * DD) + (l & 3) * 32;
    const f32x4* Qr = (const f32x4*)(q + (size_t)n * DD) + (l & 3) * 32;
    f32x4 ps = {0.f, 0.f, 0.f, 0.f};
#pragma unroll
    for (int j = 0; j < 32; ++j) ps += Mr[j] * Qr[j];
    float s = ps[0] + ps[1] + ps[2] + ps[3];
    s += __shfl_xor(s, 1);
    s += __shfl_xor(s, 2);
    float g = __shfl(s, (l & 15) * 4);  // candidate c's score lives on lanes 4c..4c+3
    mysc = (l < 16) ? g : -1e30f;       // sentinel: garbage lanes rank >= 16
  }

  // rank among 16 by fp32 score desc, tie -> lower m-index
  int rank = 0;
  for (int i = 0; i < 16; ++i) {
    float ov = __shfl(mysc, i);
    int om = __shfl(mym, i);
    rank += (ov > mysc || (ov == mysc && om < mym)) ? 1 : 0;
  }

  // lane r (r<10) <- (softmax prob, m-index) of global rank r
  float prm = 0.f;
  int mr = 0;
  for (int r = 0; r < 10; ++r) {
    u64 bal = __ballot(rank == r && l < 16);
    int sr = (int)__ffsll(bal) - 1;
    float sv = __shfl(mysc, sr);
    int sm = __shfl(mym, sr);
    float pv = __expf(sv - mx) * invZ;
    if (l == r) { prm = pv; mr = sm; }
  }

  // output accumulation: lane l handles f32x4 pairs l*2, l*2+1
  const f32x4* Q4 = (const f32x4*)(q + (size_t)n * DD);
  f32x4 q0 = Q4[l * 2], q1 = Q4[l * 2 + 1];
  f32x4 acc0a = q0 * 0.5f, acc0b = q1 * 0.5f;
  f32x4 acc1a = q0 * 0.01f, acc1b = q1 * 0.01f;

  float mt = -1e30f;
  for (int r = 0; r < 5; ++r) mt = fmaxf(mt, __shfl(prm, r));
  float Wt = 0.f;
  for (int r = 0; r < 5; ++r) Wt += __expf(__shfl(prm, r) - mt);
  float iWt = 0.5f / Wt;
  for (int r = 0; r < 5; ++r) {
    float pv = __shfl(prm, r);
    int mi = __shfl(mr, r);
    float wt = __expf(pv - mt) * iWt;
    const f32x4* M4 = (const f32x4*)(m_items + (size_t)mi * DD);
    acc0a += wt * M4[l * 2];
    acc0b += wt * M4[l * 2 + 1];
  }

  float mb = -1e30f;
  for (int r = 5; r < 10; ++r) mb = fmaxf(mb, __shfl(prm, r));
  float Wb = 0.f;
  for (int r = 5; r < 10; ++r) Wb += __expf(__shfl(prm, r) - mb);
  float iWb = 0.99f / Wb;
  for (int r = 5; r < 10; ++r) {
    float pv = __shfl(prm, r);
    int mi = __shfl(mr, r);
    float wt = __expf(pv - mb) * iWb;
    const f32x4* M4 = (const f32x4*)(m_items + (size_t)mi * DD);
    acc1a += wt * M4[l * 2];
    acc1b += wt * M4[l * 2 + 1];
  }

  f32x4* O0 = (f32x4*)(out + (size_t)n * DD);
  O0[l * 2] = acc0a;
  O0[l * 2 + 1] = acc0b;
  f32x4* O1 = (f32x4*)(out + (size_t)NQ * DD + (size_t)n * DD);
  O1[l * 2] = acc1a;
  O1[l * 2 + 1] = acc1b;
}

// ---------------- launch ----------------

extern "C" void kernel_launch(void* const* d_in, const int* in_sizes, int n_in,
                              void* d_out, int out_size, void* d_ws, size_t ws_size,
                              hipStream_t stream) {
  const float* q = (const float*)d_in[0];
  const float* m = (const float*)d_in[1];
  float* out = (float*)d_out;

  // workspace: Qb bf16 (32 MiB) | Mb bf16 (2 MiB) | SP u32 row-pairs (128 MiB)
  u16* Qb = (u16*)d_ws;
  u16* Mb = Qb + (size_t)NQ * DD;
  u32* SP = (u32*)(Mb + (size_t)MI * DD);

  cvt_kernel<<<2048, 256, 0, stream>>>(q, Qb, NQ * DD / 8);
  cvt_kernel<<<512, 256, 0, stream>>>(m, Mb, MI * DD / 8);
  gemm_kernel<<<(NQ / 128) * (MI / 128), 256, 0, stream>>>(Qb, Mb, SP);
  finish_kernel<<<NQ / 4, 256, 0, stream>>>(q, m, SP, out);
}

// Round 6
// 400.952 us; speedup vs baseline: 1.4645x; 1.4645x over previous
//
#include <hip/hip_runtime.h>
#include <hip/hip_bf16.h>

// Problem constants
#define NQ 32768
#define MI 2048
#define DD 512

typedef unsigned int u32;
typedef unsigned short u16;
typedef unsigned long long u64;

typedef __attribute__((ext_vector_type(8))) short bf16x8;  // 8 bf16 = 4 VGPRs
typedef __attribute__((ext_vector_type(4))) float f32x4;

// ---------------- helpers ----------------

__device__ __forceinline__ u16 f2bf_rne(float f) {
  u32 u = __builtin_bit_cast(u32, f);
  u += 0x7FFFu + ((u >> 16) & 1u);
  return (u16)(u >> 16);
}

__device__ __forceinline__ u16 f2h(float f) {
  return __builtin_bit_cast(u16, (_Float16)f);  // v_cvt_f16_f32 (RNE)
}

__device__ __forceinline__ float h2f(u16 h) {
  return (float)__builtin_bit_cast(_Float16, h);
}

__device__ __forceinline__ void gload16(const void* g, void* l) {
  const __attribute__((address_space(1))) u32* gp =
      (const __attribute__((address_space(1))) u32*)g;
  __attribute__((address_space(3))) u32* lp =
      (__attribute__((address_space(3))) u32*)(u32)(size_t)l;
  __builtin_amdgcn_global_load_lds(gp, lp, 16, 0, 0);
}

// ---------------- kernel 0: fp32 -> bf16 convert ----------------

__global__ __launch_bounds__(256) void cvt_kernel(const float* __restrict__ in,
                                                  u16* __restrict__ out, int n8) {
  int stride = gridDim.x * blockDim.x;
  for (int i = blockIdx.x * blockDim.x + threadIdx.x; i < n8; i += stride) {
    const f32x4* p = (const f32x4*)in + (size_t)i * 2;
    f32x4 a = p[0], b = p[1];
    uint4 o;
    o.x = (u32)f2bf_rne(a[0]) | ((u32)f2bf_rne(a[1]) << 16);
    o.y = (u32)f2bf_rne(a[2]) | ((u32)f2bf_rne(a[3]) << 16);
    o.z = (u32)f2bf_rne(b[0]) | ((u32)f2bf_rne(b[1]) << 16);
    o.w = (u32)f2bf_rne(b[2]) | ((u32)f2bf_rne(b[3]) << 16);
    ((uint4*)out)[i] = o;
  }
}

// ---------------- kernel 1: bf16 GEMM 256x256 tile -> packed fp16 row-pairs ----
// 2-phase prefetch, double-buffered LDS (128 KiB, 1 block/CU), BK=64, 512 thr
// = 8 waves in 2(M) x 4(N); each wave owns a 128x64 output sub-tile.
// m230 datapoint: this geometry at 2ph = 682 TF (refcheck'd).

__global__ __launch_bounds__(512, 2) void gemm_kernel(const u16* __restrict__ Qb,
                                                      const u16* __restrict__ Mb,
                                                      u32* __restrict__ SP) {
  __shared__ u16 As[2][256 * 64];
  __shared__ u16 Bs[2][256 * 64];
  const int t = threadIdx.x;
  const int l = t & 63, w = t >> 6;
  const int wr = w >> 2, wc = w & 3;  // wave -> (2 x 4) grid of 128x64 tiles
  // bijective chunked XCD swizzle: 1024 blocks, 128 contiguous work-ids/XCD;
  // B (2 MB bf16) stays L2-resident per XCD.
  const int bid = blockIdx.x;
  const int nb = (bid & 7) * 128 + (bid >> 3);
  const int bm = nb >> 3, bn = nb & 7;

  f32x4 acc[8][4] = {};
  const int l15 = l & 15, lg = l >> 4;

  // staging: thread t covers row (t>>3)+i*64, byte col (t&7)*16 of [256][64]
  const u16* Ag = Qb + (size_t)(bm * 256 + (t >> 3)) * DD + (t & 7) * 8;
  const u16* Bg = Mb + (size_t)(bn * 256 + (t >> 3)) * DD + (t & 7) * 8;

#define STAGE(buf, kt)                                                        \
  {                                                                           \
    _Pragma("unroll") for (int i = 0; i < 4; ++i) {                           \
      gload16(Ag + (size_t)i * 64 * DD + (kt), (char*)As[buf] + t * 16 + i * 8192); \
      gload16(Bg + (size_t)i * 64 * DD + (kt), (char*)Bs[buf] + t * 16 + i * 8192); \
    }                                                                         \
  }

  STAGE(0, 0);
  __syncthreads();  // vmcnt(0) drain: buf0 ready

#pragma unroll
  for (int t8 = 0; t8 < 8; ++t8) {
    const int cur = t8 & 1;
    if (t8 < 7) STAGE(cur ^ 1, (t8 + 1) * 64);  // prefetch flies during compute
#pragma unroll
    for (int ks = 0; ks < 2; ++ks) {
      const int kk = ks * 32 + lg * 8;
      bf16x8 af[8], bfr[4];
#pragma unroll
      for (int mi = 0; mi < 8; ++mi)
        af[mi] = *(const bf16x8*)&As[cur][(wr * 128 + mi * 16 + l15) * 64 + kk];
#pragma unroll
      for (int ni = 0; ni < 4; ++ni)
        bfr[ni] = *(const bf16x8*)&Bs[cur][(wc * 64 + ni * 16 + l15) * 64 + kk];
#pragma unroll
      for (int mi = 0; mi < 8; ++mi)
#pragma unroll
        for (int ni = 0; ni < 4; ++ni)
          acc[mi][ni] = __builtin_amdgcn_mfma_f32_16x16x32_bf16(
              af[mi], bfr[ni], acc[mi][ni], 0, 0, 0);
    }
    // single barrier/K-step: drain ensures this iter's prefetch landed AND all
    // waves finished reading buf[cur] before next iter's STAGE overwrites it.
    if (t8 < 7) __syncthreads();
  }
#undef STAGE

  // epilogue: C/D layout col=lane&15, row=(lane>>4)*4+reg (m89-verified).
  // rows r0+mi*16 .. +3 consecutive, r0 multiple of 4 -> two u32 row-pair stores.
  const int r0 = bm * 256 + wr * 128 + (l >> 4) * 4;
  const int c0 = bn * 256 + wc * 64 + l15;
  const int p0 = r0 >> 1;
#pragma unroll
  for (int mi = 0; mi < 8; ++mi)
#pragma unroll
    for (int ni = 0; ni < 4; ++ni) {
      u32 lo = (u32)f2h(acc[mi][ni][0]) | ((u32)f2h(acc[mi][ni][1]) << 16);
      u32 hi = (u32)f2h(acc[mi][ni][2]) | ((u32)f2h(acc[mi][ni][3]) << 16);
      size_t base = (size_t)(p0 + mi * 8) * MI + (c0 + ni * 16);
      SP[base] = lo;
      SP[base + MI] = hi;
    }
}

// ---------------- kernel 2: top-16 select (round-3 form, 179.8us measured) ----
// One wave per row n; p=n>>1, h=n&1 pick the fp16 half of SP[p][*].
// Lane l, slot s (0..31): m = (s>>2)*256 + l*4 + (s&3).

#define MAX8T(b) fmaxf(fmaxf(fmaxf(k[b], k[b + 1]), fmaxf(k[b + 2], k[b + 3])), \
                       fmaxf(fmaxf(k[b + 4], k[b + 5]), fmaxf(k[b + 6], k[b + 7])))

#define REMOVE_GRP(b, gvar)                                   \
  {                                                           \
    _Pragma("unroll") for (int j = 0; j < 8; ++j)             \
        k[b + j] = (k[b + j] == gmax) ? -3e38f : k[b + j];    \
    gvar = MAX8T(b);                                          \
  }

__global__ __launch_bounds__(256) void finish_kernel(const float* __restrict__ q,
                                                     const float* __restrict__ m_items,
                                                     const u32* __restrict__ SP,
                                                     float* __restrict__ out) {
  const int w = threadIdx.x >> 6, l = threadIdx.x & 63;
  const int n = blockIdx.x * 4 + w;
  const int p = n >> 1, h = n & 1;

  const uint4* Sr = (const uint4*)(SP + (size_t)p * MI);
  float k[32];
#pragma unroll
  for (int i = 0; i < 8; ++i) {
    uint4 c = Sr[i * 64 + l];
    u32 wd[4] = {c.x, c.y, c.z, c.w};
#pragma unroll
    for (int j = 0; j < 4; ++j) {
      u16 hb = h ? (u16)(wd[j] >> 16) : (u16)(wd[j] & 0xFFFFu);
      float f = h2f(hb);
      int s = i * 4 + j;
      // slot tag in 5 low mantissa bits (scores fp16-derived: distinct scores
      // differ at bit>=13, tag never flips an ordering)
      k[s] = __builtin_bit_cast(float,
                                (__builtin_bit_cast(u32, f) & ~31u) | (u32)(31 - s));
    }
  }

  // row max + sumexp
  float mx = k[0];
#pragma unroll
  for (int j = 1; j < 32; ++j) mx = fmaxf(mx, k[j]);
  for (int off = 32; off >= 1; off >>= 1) mx = fmaxf(mx, __shfl_xor(mx, off));
  float se = 0.f;
#pragma unroll
  for (int j = 0; j < 32; ++j) se += __expf(k[j] - mx);
  for (int off = 32; off >= 1; off >>= 1) se += __shfl_xor(se, off);
  const float invZ = 1.0f / se;

  // group maxima (4 groups of 8)
  float g0 = MAX8T(0), g1 = MAX8T(8), g2 = MAX8T(16), g3 = MAX8T(24);
  float pk = fmaxf(fmaxf(g0, g1), fmaxf(g2, g3));

  int mym = 0x7FFFFFFF;
  float mysc = -1e30f;
#pragma unroll 1
  for (int c = 0; c < 16; ++c) {
    float gmax = pk;
    for (int off = 32; off >= 1; off >>= 1) gmax = fmaxf(gmax, __shfl_xor(gmax, off));
    u32 gb = __builtin_bit_cast(u32, gmax);
    int jw = 31 - (int)(gb & 31u);
    u64 bal = __ballot(pk == gmax);
    int wl = (int)__ffsll(bal) - 1;
    int mwin = ((jw >> 2) << 8) + wl * 4 + (jw & 3);
    if (l == c) mym = mwin;
    int grp = __builtin_amdgcn_readfirstlane(jw >> 3);
    switch (grp) {
      case 0: REMOVE_GRP(0, g0); break;
      case 1: REMOVE_GRP(8, g1); break;
      case 2: REMOVE_GRP(16, g2); break;
      default: REMOVE_GRP(24, g3); break;
    }
    pk = fmaxf(fmaxf(g0, g1), fmaxf(g2, g3));
  }

  // exact fp32 rescore of the 16 candidates (serial, coalesced broadcast loads)
  const f32x4* Q4 = (const f32x4*)(q + (size_t)n * DD);
  f32x4 q0 = Q4[l * 2], q1 = Q4[l * 2 + 1];
  for (int c = 0; c < 16; ++c) {
    int mc = __shfl(mym, c);
    const f32x4* M4 = (const f32x4*)(m_items + (size_t)mc * DD);
    f32x4 a = M4[l * 2], b = M4[l * 2 + 1];
    float pr = a[0] * q0[0] + a[1] * q0[1] + a[2] * q0[2] + a[3] * q0[3] +
               b[0] * q1[0] + b[1] * q1[1] + b[2] * q1[2] + b[3] * q1[3];
    for (int off = 32; off >= 1; off >>= 1) pr += __shfl_xor(pr, off);
    if (l == c) mysc = pr;
  }

  // rank among 16 by fp32 score desc, tie -> lower m-index
  int rank = 0;
  for (int i = 0; i < 16; ++i) {
    float ov = __shfl(mysc, i);
    int om = __shfl(mym, i);
    rank += (ov > mysc || (ov == mysc && om < mym)) ? 1 : 0;
  }

  // lane r (r<10) <- (softmax prob, m-index) of global rank r
  float prm = 0.f;
  int mr = 0;
  for (int r = 0; r < 10; ++r) {
    u64 bal = __ballot(rank == r);
    int sr = (int)__ffsll(bal) - 1;
    float sv = __shfl(mysc, sr);
    int sm = __shfl(mym, sr);
    float pv = __expf(sv - mx) * invZ;
    if (l == r) { prm = pv; mr = sm; }
  }

  // grouped 5-way softmax + weighted key gather
  f32x4 acc0a = q0 * 0.5f, acc0b = q1 * 0.5f;
  f32x4 acc1a = q0 * 0.01f, acc1b = q1 * 0.01f;

  float mt = -1e30f;
  for (int r = 0; r < 5; ++r) mt = fmaxf(mt, __shfl(prm, r));
  float Wt = 0.f;
  for (int r = 0; r < 5; ++r) Wt += __expf(__shfl(prm, r) - mt);
  float iWt = 0.5f / Wt;
  for (int r = 0; r < 5; ++r) {
    float pv = __shfl(prm, r);
    int mi = __shfl(mr, r);
    float wt = __expf(pv - mt) * iWt;
    const f32x4* M4 = (const f32x4*)(m_items + (size_t)mi * DD);
    acc0a += wt * M4[l * 2];
    acc0b += wt * M4[l * 2 + 1];
  }

  float mb = -1e30f;
  for (int r = 5; r < 10; ++r) mb = fmaxf(mb, __shfl(prm, r));
  float Wb = 0.f;
  for (int r = 5; r < 10; ++r) Wb += __expf(__shfl(prm, r) - mb);
  float iWb = 0.99f / Wb;
  for (int r = 5; r < 10; ++r) {
    float pv = __shfl(prm, r);
    int mi = __shfl(mr, r);
    float wt = __expf(pv - mb) * iWb;
    const f32x4* M4 = (const f32x4*)(m_items + (size_t)mi * DD);
    acc1a += wt * M4[l * 2];
    acc1b += wt * M4[l * 2 + 1];
  }

  f32x4* O0 = (f32x4*)(out + (size_t)n * DD);
  O0[l * 2] = acc0a;
  O0[l * 2 + 1] = acc0b;
  f32x4* O1 = (f32x4*)(out + (size_t)NQ * DD + (size_t)n * DD);
  O1[l * 2] = acc1a;
  O1[l * 2 + 1] = acc1b;
}

// ---------------- launch ----------------

extern "C" void kernel_launch(void* const* d_in, const int* in_sizes, int n_in,
                              void* d_out, int out_size, void* d_ws, size_t ws_size,
                              hipStream_t stream) {
  const float* q = (const float*)d_in[0];
  const float* m = (const float*)d_in[1];
  float* out = (float*)d_out;

  // workspace: Qb bf16 (32 MiB) | Mb bf16 (2 MiB) | SP u32 row-pairs (128 MiB)
  u16* Qb = (u16*)d_ws;
  u16* Mb = Qb + (size_t)NQ * DD;
  u32* SP = (u32*)(Mb + (size_t)MI * DD);

  cvt_kernel<<<2048, 256, 0, stream>>>(q, Qb, NQ * DD / 8);
  cvt_kernel<<<512, 256, 0, stream>>>(m, Mb, MI * DD / 8);
  gemm_kernel<<<(NQ / 256) * (MI / 256), 512, 0, stream>>>(Qb, Mb, SP);
  finish_kernel<<<NQ / 4, 256, 0, stream>>>(q, m, SP, out);
}